// Round 8
// baseline (272.161 us; speedup 1.0000x reference)
//
#include <hip/hip_runtime.h>
#include <math.h>

#define N 1024
#define BATCH 32
#define NT 512
#define ROWS 4
#define RSTRIDE 1092                      // cf per row: 1024 + 64 pad + 4 stagger
#define P16(i) ((i) + ((i) >> 4))         // shg pad: +1 cf per 16
#define PADC(i) ((i) + ((i) >> 5))        // hilbert pad (round-5 measured config)

// wave-local LDS ordering
#define WSYNC() asm volatile("s_waitcnt lgkmcnt(0)" ::: "memory")

typedef float2 cf;
__device__ __forceinline__ cf cadd(cf a, cf b){ return make_float2(a.x+b.x, a.y+b.y); }
__device__ __forceinline__ cf csub(cf a, cf b){ return make_float2(a.x-b.x, a.y-b.y); }
__device__ __forceinline__ cf cmul(cf a, cf b){ return make_float2(a.x*b.x - a.y*b.y, a.x*b.y + a.y*b.x); }

// exp(-2*pi*i*jn), jn in revolutions (v_sin/v_cos take revolutions)
__device__ __forceinline__ cf twiddle(float jn){
    float s = __builtin_amdgcn_sinf(jn);
    float c = __builtin_amdgcn_cosf(jn);
    return make_float2(c, -s);
}

__device__ __forceinline__ int rev10(int m){
    int r = (int)(__brev((unsigned)m) >> 22);
    return ((r & 0x155) << 1) | ((r >> 1) & 0x155);
}

// radix-4 DIF butterfly core
__device__ __forceinline__ void bfly(cf x0, cf x1, cf x2, cf x3,
                                     cf& y0, cf& y1, cf& y2, cf& y3){
    cf A = cadd(x0,x2), Bs = cadd(x1,x3);
    cf C = csub(x0,x2), D = csub(x1,x3);
    cf Dmi = make_float2(D.y, -D.x);
    y0 = cadd(A,Bs); y1 = cadd(C,Dmi); y2 = csub(A,Bs); y3 = csub(C,Dmi);
}

// in-place LDS butterfly with register twiddles, pad-16 layout
__device__ __forceinline__ void dif4p(cf* w, int base, int q, cf w1, cf w2, cf w3){
    cf x0 = w[P16(base)], x1 = w[P16(base+q)], x2 = w[P16(base+2*q)], x3 = w[P16(base+3*q)];
    cf y0, y1, y2, y3; bfly(x0,x1,x2,x3,y0,y1,y2,y3);
    w[P16(base)]     = y0;
    w[P16(base+q)]   = cmul(y1,w1);
    w[P16(base+2*q)] = cmul(y2,w2);
    w[P16(base+3*q)] = cmul(y3,w3);
}

// ---- hilbert_k helpers (pad-32, round-5 verified) ----
__device__ __forceinline__ void dif4h(cf* w, int base, int q, float jn){
    cf x0 = w[PADC(base)], x1 = w[PADC(base+q)], x2 = w[PADC(base+2*q)], x3 = w[PADC(base+3*q)];
    cf y0, y1, y2, y3; bfly(x0,x1,x2,x3,y0,y1,y2,y3);
    cf w1 = twiddle(jn), w2 = cmul(w1,w1), w3 = cmul(w2,w1);
    w[PADC(base)]     = y0;
    w[PADC(base+q)]   = cmul(y1,w1);
    w[PADC(base+2*q)] = cmul(y2,w2);
    w[PADC(base+3*q)] = cmul(y3,w3);
}
template<int LOG2N>
__device__ __forceinline__ void dif_stage(cf* w, int t){
    const int n = 1 << LOG2N, q = n >> 2;
    int j = t & (q - 1);
    int base = ((t >> (LOG2N - 2)) << LOG2N) + j;
    dif4h(w, base, q, (float)j * (1.0f / (float)n));
}
template<int LOG2N>
__device__ __forceinline__ void dit_stage(cf* w, int t){
    const int n = 1 << LOG2N, q = n >> 2;
    int j = t & (q - 1);
    int base = ((t >> (LOG2N - 2)) << LOG2N) + j;
    cf x0 = w[PADC(base)], x1 = w[PADC(base+q)], x2 = w[PADC(base+2*q)], x3 = w[PADC(base+3*q)];
    cf w1 = twiddle((float)j * (1.0f / (float)n));
    cf w2 = cmul(w1,w1), w3 = cmul(w2,w1);
    x1 = cmul(x1,w1); x2 = cmul(x2,w2); x3 = cmul(x3,w3);
    cf y0, y1, y2, y3; bfly(x0,x1,x2,x3,y0,y1,y2,y3);
    w[PADC(base)] = y0; w[PADC(base+q)] = y1; w[PADC(base+2*q)] = y2; w[PADC(base+3*q)] = y3;
}

// ---------------------------------------------------------------------------
// hilbert_k: analytic signal a, ca = a*SF, fused label MSE -> mseJ[b].
// (round-5 verified; unchanged)
// ---------------------------------------------------------------------------
__global__ __launch_bounds__(256) void hilbert_k(const float* __restrict__ pred,
                                                 const float* __restrict__ label,
                                                 cf* __restrict__ a,
                                                 cf* __restrict__ ca,
                                                 float* __restrict__ mseJ) {
    __shared__ cf wk[1056];
    __shared__ float rbuf[4][4];
    __shared__ int ibuf[4][4];
    __shared__ int s_first, s_last;
    int t = threadIdx.x, b = blockIdx.x;
    for (int i = t; i < N; i += 256) wk[PADC(i)] = make_float2(pred[b * N + i], 0.f);
    __syncthreads();
    dif_stage<10>(wk, t); __syncthreads();
    dif_stage<8>(wk, t);  __syncthreads();
    dif_stage<6>(wk, t);  __syncthreads();
    dif_stage<4>(wk, t);  __syncthreads();
    dif_stage<2>(wk, t);  __syncthreads();
    for (int i = t; i < N; i += 256) {
        int k = rev10(i);
        float f = (k < 512) ? 0.f : ((k == 512) ? 1.f : 2.f);
        cf v = wk[PADC(i)];
        wk[PADC(i)] = make_float2(f * v.x, -f * v.y);
    }
    __syncthreads();
    dit_stage<2>(wk, t);  __syncthreads();
    dit_stage<4>(wk, t);  __syncthreads();
    dit_stage<6>(wk, t);  __syncthreads();
    dit_stage<8>(wk, t);  __syncthreads();
    dit_stage<10>(wk, t); __syncthreads();
    const float sc = 1.f / (float)N;
    for (int i = t; i < N; i += 256) {
        cf v = wk[PADC(i)];
        cf av = make_float2(v.x * sc, -v.y * sc);
        wk[PADC(i)] = av;
        a[b * N + i] = av;
        float p = (float)(3.525 * (double)(i - 512));
        float s_, c_;
        sincosf(p, &s_, &c_);
        ca[b * N + i] = make_float2(av.x * c_ + av.y * s_, av.y * c_ - av.x * s_);
    }
    __syncthreads();

    int w = t >> 6, lane = t & 63;
    int mnR = N, mxR = -1, mnI = N, mxI = -1;
    for (int n = t; n < N; n += 256) {
        float lr = label[b * 2 * N + n];
        float li = label[b * 2 * N + N + n];
        if (fabsf(lr) > 0.01f) { mnR = min(mnR, n); mxR = max(mxR, n); }
        if (fabsf(li) > 0.01f) { mnI = min(mnI, n); mxI = max(mxI, n); }
    }
    for (int o = 32; o > 0; o >>= 1) {
        mnR = min(mnR, __shfl_down(mnR, o));
        mxR = max(mxR, __shfl_down(mxR, o));
        mnI = min(mnI, __shfl_down(mnI, o));
        mxI = max(mxI, __shfl_down(mxI, o));
    }
    if (lane == 0) { ibuf[w][0] = mnR; ibuf[w][1] = mxR; ibuf[w][2] = mnI; ibuf[w][3] = mxI; }
    __syncthreads();
    if (t == 0) {
        int a0 = N, a1 = -1, a2 = N, a3 = -1;
        for (int i = 0; i < 4; ++i) {
            a0 = min(a0, ibuf[i][0]); a1 = max(a1, ibuf[i][1]);
            a2 = min(a2, ibuf[i][2]); a3 = max(a3, ibuf[i][3]);
        }
        int fr   = (a0 == N) ? 0 : a0;
        int lstR = (a1 < 0) ? (N - 1) : a1;
        int fi   = (a2 == N) ? 0 : a2;
        int lstI = (a3 < 0) ? (N - 1) : a3;
        s_first = min(fr, fi);
        s_last  = max(lstR, lstI);
    }
    __syncthreads();
    int first = s_first, last = s_last;

    float m_r = 0.f, m_i = 0.f, m_n = 0.f, m_p = 0.f;
    for (int n = t; n < N; n += 256) {
        cf p = wk[PADC(n)];
        float lr = label[b * 2 * N + n];
        float li = label[b * 2 * N + N + n];
        bool in = (n >= first) && (n < last);
        float pm  = in ? 10.f : 1.f;
        float phm = in ? 1.f : 0.f;
        float dr = p.x - lr, di = p.y - li;
        float dn = (p.x * p.x + p.y * p.y) - (lr * lr + li * li);
        float dp = atan2f(p.y, p.x) - atan2f(li, lr);
        m_r += dr * dr * pm;
        m_i += di * di * pm;
        m_n += dn * dn * pm;
        m_p += dp * dp * phm;
    }
    for (int o = 32; o > 0; o >>= 1) {
        m_r += __shfl_down(m_r, o);
        m_i += __shfl_down(m_i, o);
        m_n += __shfl_down(m_n, o);
        m_p += __shfl_down(m_p, o);
    }
    if (lane == 0) { rbuf[w][0] = m_r; rbuf[w][1] = m_i; rbuf[w][2] = m_n; rbuf[w][3] = m_p; }
    __syncthreads();
    if (t == 0) {
        float s = 0.f;
        for (int i = 0; i < 4; ++i) s += rbuf[i][0] + rbuf[i][1] + rbuf[i][2] + rbuf[i][3];
        mseJ[b] = s * (1.f / (float)N) * 0.25f;
    }
}

// ---------------------------------------------------------------------------
// shg_k: round-7 structure, plus: the 16 tref values each fused-phase thread
// needs are prefetched into registers AT KERNEL ENTRY (addresses depend only
// on blockIdx/threadIdx) so their latency is hidden under the FFT stages.
// ---------------------------------------------------------------------------
__global__ __launch_bounds__(NT, 8) void shg_k(const cf* __restrict__ a,
                                               const cf* __restrict__ cag,
                                               const float* __restrict__ tref,
                                               float* __restrict__ Praw,
                                               float* __restrict__ Prt,
                                               float* __restrict__ Pmax,
                                               float* __restrict__ Pt,
                                               float* __restrict__ Ptt) {
    __shared__ cf wk[ROWS * RSTRIDE];
    int t = threadIdx.x, blk = blockIdx.x;
    int b = blk >> 8;
    int dg = (blk & 255) << 2;            // delay-indices dg..dg+3
    const cf* arow  = a   + b * N;
    const cf* carow = cag + b * N;
    int bt = t & 255, rg = t >> 8;        // butterfly id, row-pair

    // ---- prefetch: 16 tref values for the fused phase (waves 0-3 only) ----
    float tvv[16];
    if (t < 256) {
        int r = t >> 6, g = t & 63;
        int bd_ = b * N + dg + r;
        const float* trow = tref + ((size_t)bd_ << 10);
        int kb = ((g & 3) << 4) | (g & 12) | (g >> 4);
#pragma unroll
        for (int u = 0; u < 4; ++u)
#pragma unroll
            for (int m = 0; m < 4; ++m)
                tvv[4*u + m] = trow[(((m + 2) & 3) << 8) | (u << 6) | kb];
    }

    // ---- stage 1 (q=256): twiddles + ca loads shared across 2 rows ----
    {
        cf w1 = twiddle((float)bt * (1.0f / 1024.0f));
        cf w2 = cmul(w1,w1), w3 = cmul(w2,w1);
        cf cav[4];
#pragma unroll
        for (int k = 0; k < 4; ++k) cav[k] = carow[(bt + 256*k + 512) & 1023];
#pragma unroll
        for (int rr = 0; rr < 2; ++rr) {
            int r = rg * 2 + rr;
            int d = dg + r;
            cf x[4];
#pragma unroll
            for (int k = 0; k < 4; ++k)
                x[k] = cmul(cav[k], arow[(bt + 256*k - d) & 1023]);
            cf y0, y1, y2, y3; bfly(x[0],x[1],x[2],x[3],y0,y1,y2,y3);
            cf* w = wk + r * RSTRIDE;
            w[P16(bt)]     = y0;
            w[P16(bt+256)] = cmul(y1,w1);
            w[P16(bt+512)] = cmul(y2,w2);
            w[P16(bt+768)] = cmul(y3,w3);
        }
    }
    __syncthreads();
    // ---- stage 2 (q=64): wave-local per row-half ----
    {
        int j = bt & 63;
        int base = ((bt >> 6) << 8) + j;
        cf w1 = twiddle((float)j * (1.0f / 256.0f));
        cf w2 = cmul(w1,w1), w3 = cmul(w2,w1);
#pragma unroll
        for (int rr = 0; rr < 2; ++rr) dif4p(wk + (rg*2+rr) * RSTRIDE, base, 64, w1, w2, w3);
    }
    WSYNC();
    // ---- stage 3 (q=16): still wave-local per row-half ----
    {
        int j = bt & 15;
        int base = ((bt >> 4) << 6) + j;
        cf w1 = twiddle((float)j * (1.0f / 64.0f));
        cf w2 = cmul(w1,w1), w3 = cmul(w2,w1);
#pragma unroll
        for (int rr = 0; rr < 2; ++rr) dif4p(wk + (rg*2+rr) * RSTRIDE, base, 16, w1, w2, w3);
    }
    __syncthreads();   // redistribution: fused stage crosses row-halves

    // ---- fused stages 4+5: in-register 16-pt DFT; wave w (w<4) = row w ----
    if (t < 256) {
        const cf W1 = { 0.923879533f, -0.382683432f};
        const cf W2 = { 0.707106781f, -0.707106781f};
        const cf W3 = { 0.382683432f, -0.923879533f};
        const cf W6 = {-0.707106781f, -0.707106781f};
        const cf W9 = {-0.923879533f,  0.382683432f};
        int r = t >> 6;                  // row = wave index
        int g = t & 63;                  // 16-block within row
        cf* w = wk + r * RSTRIDE;
        cf v[16];
        int base = 17 * g;               // P16(16g+k) = 17g+k, k<16
#pragma unroll
        for (int k = 0; k < 16; ++k) v[k] = w[base + k];
        cf o[16];
        bfly(v[0], v[4], v[8], v[12], o[0], o[4], o[8],  o[12]);
        { cf y0,y1,y2,y3; bfly(v[1],v[5],v[9], v[13],y0,y1,y2,y3);
          o[1]=y0; o[5]=cmul(y1,W1); o[9]=cmul(y2,W2); o[13]=cmul(y3,W3); }
        { cf y0,y1,y2,y3; bfly(v[2],v[6],v[10],v[14],y0,y1,y2,y3);
          o[2]=y0; o[6]=cmul(y1,W2); o[10]=make_float2(y2.y,-y2.x); o[14]=cmul(y3,W6); }
        { cf y0,y1,y2,y3; bfly(v[3],v[7],v[11],v[15],y0,y1,y2,y3);
          o[3]=y0; o[7]=cmul(y1,W3); o[11]=cmul(y2,W6); o[15]=cmul(y3,W9); }

        float sraw = 0.f, srt = 0.f, mx = 0.f, st = 0.f, stt = 0.f;
        int bd = b * N + dg + r;
#pragma unroll
        for (int u = 0; u < 4; ++u) {
            cf y0, y1, y2, y3;
            bfly(o[4*u], o[4*u+1], o[4*u+2], o[4*u+3], y0, y1, y2, y3);
            cf ys[4] = {y0, y1, y2, y3};
#pragma unroll
            for (int m = 0; m < 4; ++m) {
                float m2 = ys[m].x * ys[m].x + ys[m].y * ys[m].y;
                float tv = tvv[4*u + m];
                sraw += m2;
                srt += m2 * tv;
                mx = fmaxf(mx, m2);
                st += tv;
                stt += tv * tv;
            }
        }
        // full-wave reduction: wave r covers g = 0..63 = entire row r
        for (int o_ = 32; o_ > 0; o_ >>= 1) {
            sraw += __shfl_down(sraw, o_);
            srt  += __shfl_down(srt, o_);
            mx    = fmaxf(mx, __shfl_down(mx, o_));
            st   += __shfl_down(st, o_);
            stt  += __shfl_down(stt, o_);
        }
        if ((t & 63) == 0) {
            Praw[bd] = sraw; Prt[bd] = srt; Pmax[bd] = mx; Pt[bd] = st; Ptt[bd] = stt;
        }
    }
}

// ---------------------------------------------------------------------------
// loss_k: per batch — frog from row partials + mseJ -> atomic mean.
// ---------------------------------------------------------------------------
__global__ __launch_bounds__(256) void loss_k(const float* __restrict__ Praw,
                                              const float* __restrict__ Prt,
                                              const float* __restrict__ Pmax,
                                              const float* __restrict__ Pt,
                                              const float* __restrict__ Ptt,
                                              const float* __restrict__ mseJ,
                                              float* __restrict__ out) {
    __shared__ float rbuf[4][8];
    int tid = threadIdx.x, b = blockIdx.x;
    int w = tid >> 6, lane = tid & 63;
    float sr = 0.f, srt = 0.f, mx = 0.f, st = 0.f, stt = 0.f;
    for (int i = tid; i < N; i += 256) {
        int idx = b * N + i;
        sr += Praw[idx]; srt += Prt[idx]; mx = fmaxf(mx, Pmax[idx]);
        st += Pt[idx];   stt += Ptt[idx];
    }
    for (int o = 32; o > 0; o >>= 1) {
        sr  += __shfl_down(sr, o);
        srt += __shfl_down(srt, o);
        mx   = fmaxf(mx, __shfl_down(mx, o));
        st  += __shfl_down(st, o);
        stt += __shfl_down(stt, o);
    }
    if (lane == 0) {
        rbuf[w][0] = sr; rbuf[w][1] = srt; rbuf[w][2] = mx;
        rbuf[w][3] = st; rbuf[w][4] = stt;
    }
    __syncthreads();
    if (tid == 0) {
        float A0 = 0.f, A1 = 0.f, A2 = 0.f, A3 = 0.f, A4 = 0.f;
        for (int i = 0; i < 4; ++i) {
            A0 += rbuf[i][0]; A1 += rbuf[i][1]; A2 = fmaxf(A2, rbuf[i][2]);
            A3 += rbuf[i][3]; A4 += rbuf[i][4];
        }
        float mu = (A1 / A2) / A4;
        float diff = A0 / A2 - mu * A3;
        float frog = fabsf(diff) * (1.f / (float)N);
        atomicAdd(out, (mseJ[b] + frog) * (1.f / (float)BATCH));
    }
}

extern "C" void kernel_launch(void* const* d_in, const int* in_sizes, int n_in,
                              void* d_out, int out_size, void* d_ws, size_t ws_size,
                              hipStream_t stream) {
    (void)in_sizes; (void)n_in; (void)out_size; (void)ws_size;
    const float* pred  = (const float*)d_in[0];
    const float* label = (const float*)d_in[1];
    const float* shg   = (const float*)d_in[2];
    float* out = (float*)d_out;

    char* ws = (char*)d_ws;
    cf* a   = (cf*)ws;
    cf* ca  = a + (size_t)BATCH * N;
    float* mseJ = (float*)(ca + (size_t)BATCH * N);
    float* P = mseJ + BATCH;
    float* Praw = P;
    float* Prt  = P + (size_t)BATCH * N;
    float* Pmax = P + 2 * (size_t)BATCH * N;
    float* Pt   = P + 3 * (size_t)BATCH * N;
    float* Ptt  = P + 4 * (size_t)BATCH * N;

    hipMemsetAsync(d_out, 0, sizeof(float), stream);
    hilbert_k<<<BATCH, 256, 0, stream>>>(pred, label, a, ca, mseJ);
    shg_k<<<BATCH * 256, NT, 0, stream>>>(a, ca, shg, Praw, Prt, Pmax, Pt, Ptt);
    loss_k<<<BATCH, 256, 0, stream>>>(Praw, Prt, Pmax, Pt, Ptt, mseJ, out);
}

// Round 9
// 230.025 us; speedup vs baseline: 1.1832x; 1.1832x over previous
//
#include <hip/hip_runtime.h>
#include <math.h>

#define N 1024
#define BATCH 32
#define NT 512
#define ROWS 4
#define RSTRIDE 1092                      // cf per row: 1024 + 64 pad + 4 stagger
#define P16(i) ((i) + ((i) >> 4))         // shg pad: +1 cf per 16
#define PADC(i) ((i) + ((i) >> 5))        // hilbert pad (round-5 measured config)

// wave-local LDS ordering
#define WSYNC() asm volatile("s_waitcnt lgkmcnt(0)" ::: "memory")

typedef float2 cf;
__device__ __forceinline__ cf cadd(cf a, cf b){ return make_float2(a.x+b.x, a.y+b.y); }
__device__ __forceinline__ cf csub(cf a, cf b){ return make_float2(a.x-b.x, a.y-b.y); }
__device__ __forceinline__ cf cmul(cf a, cf b){ return make_float2(a.x*b.x - a.y*b.y, a.x*b.y + a.y*b.x); }

// exp(-2*pi*i*jn), jn in revolutions (v_sin/v_cos take revolutions)
__device__ __forceinline__ cf twiddle(float jn){
    float s = __builtin_amdgcn_sinf(jn);
    float c = __builtin_amdgcn_cosf(jn);
    return make_float2(c, -s);
}

__device__ __forceinline__ int rev10(int m){
    int r = (int)(__brev((unsigned)m) >> 22);
    return ((r & 0x155) << 1) | ((r >> 1) & 0x155);
}

// radix-4 DIF butterfly core
__device__ __forceinline__ void bfly(cf x0, cf x1, cf x2, cf x3,
                                     cf& y0, cf& y1, cf& y2, cf& y3){
    cf A = cadd(x0,x2), Bs = cadd(x1,x3);
    cf C = csub(x0,x2), D = csub(x1,x3);
    cf Dmi = make_float2(D.y, -D.x);
    y0 = cadd(A,Bs); y1 = cadd(C,Dmi); y2 = csub(A,Bs); y3 = csub(C,Dmi);
}

// in-place LDS butterfly with register twiddles, pad-16 layout
__device__ __forceinline__ void dif4p(cf* w, int base, int q, cf w1, cf w2, cf w3){
    cf x0 = w[P16(base)], x1 = w[P16(base+q)], x2 = w[P16(base+2*q)], x3 = w[P16(base+3*q)];
    cf y0, y1, y2, y3; bfly(x0,x1,x2,x3,y0,y1,y2,y3);
    w[P16(base)]     = y0;
    w[P16(base+q)]   = cmul(y1,w1);
    w[P16(base+2*q)] = cmul(y2,w2);
    w[P16(base+3*q)] = cmul(y3,w3);
}

// ---- hilbert_k helpers (pad-32, round-5 verified) ----
__device__ __forceinline__ void dif4h(cf* w, int base, int q, float jn){
    cf x0 = w[PADC(base)], x1 = w[PADC(base+q)], x2 = w[PADC(base+2*q)], x3 = w[PADC(base+3*q)];
    cf y0, y1, y2, y3; bfly(x0,x1,x2,x3,y0,y1,y2,y3);
    cf w1 = twiddle(jn), w2 = cmul(w1,w1), w3 = cmul(w2,w1);
    w[PADC(base)]     = y0;
    w[PADC(base+q)]   = cmul(y1,w1);
    w[PADC(base+2*q)] = cmul(y2,w2);
    w[PADC(base+3*q)] = cmul(y3,w3);
}
template<int LOG2N>
__device__ __forceinline__ void dif_stage(cf* w, int t){
    const int n = 1 << LOG2N, q = n >> 2;
    int j = t & (q - 1);
    int base = ((t >> (LOG2N - 2)) << LOG2N) + j;
    dif4h(w, base, q, (float)j * (1.0f / (float)n));
}
template<int LOG2N>
__device__ __forceinline__ void dit_stage(cf* w, int t){
    const int n = 1 << LOG2N, q = n >> 2;
    int j = t & (q - 1);
    int base = ((t >> (LOG2N - 2)) << LOG2N) + j;
    cf x0 = w[PADC(base)], x1 = w[PADC(base+q)], x2 = w[PADC(base+2*q)], x3 = w[PADC(base+3*q)];
    cf w1 = twiddle((float)j * (1.0f / (float)n));
    cf w2 = cmul(w1,w1), w3 = cmul(w2,w1);
    x1 = cmul(x1,w1); x2 = cmul(x2,w2); x3 = cmul(x3,w3);
    cf y0, y1, y2, y3; bfly(x0,x1,x2,x3,y0,y1,y2,y3);
    w[PADC(base)] = y0; w[PADC(base+q)] = y1; w[PADC(base+2*q)] = y2; w[PADC(base+3*q)] = y3;
}

// ---------------------------------------------------------------------------
// hilbert_k: analytic signal a, ca = a*SF, fused label MSE -> mseJ[b].
// (round-5 verified; unchanged)
// ---------------------------------------------------------------------------
__global__ __launch_bounds__(256) void hilbert_k(const float* __restrict__ pred,
                                                 const float* __restrict__ label,
                                                 cf* __restrict__ a,
                                                 cf* __restrict__ ca,
                                                 float* __restrict__ mseJ) {
    __shared__ cf wk[1056];
    __shared__ float rbuf[4][4];
    __shared__ int ibuf[4][4];
    __shared__ int s_first, s_last;
    int t = threadIdx.x, b = blockIdx.x;
    for (int i = t; i < N; i += 256) wk[PADC(i)] = make_float2(pred[b * N + i], 0.f);
    __syncthreads();
    dif_stage<10>(wk, t); __syncthreads();
    dif_stage<8>(wk, t);  __syncthreads();
    dif_stage<6>(wk, t);  __syncthreads();
    dif_stage<4>(wk, t);  __syncthreads();
    dif_stage<2>(wk, t);  __syncthreads();
    for (int i = t; i < N; i += 256) {
        int k = rev10(i);
        float f = (k < 512) ? 0.f : ((k == 512) ? 1.f : 2.f);
        cf v = wk[PADC(i)];
        wk[PADC(i)] = make_float2(f * v.x, -f * v.y);
    }
    __syncthreads();
    dit_stage<2>(wk, t);  __syncthreads();
    dit_stage<4>(wk, t);  __syncthreads();
    dit_stage<6>(wk, t);  __syncthreads();
    dit_stage<8>(wk, t);  __syncthreads();
    dit_stage<10>(wk, t); __syncthreads();
    const float sc = 1.f / (float)N;
    for (int i = t; i < N; i += 256) {
        cf v = wk[PADC(i)];
        cf av = make_float2(v.x * sc, -v.y * sc);
        wk[PADC(i)] = av;
        a[b * N + i] = av;
        float p = (float)(3.525 * (double)(i - 512));
        float s_, c_;
        sincosf(p, &s_, &c_);
        ca[b * N + i] = make_float2(av.x * c_ + av.y * s_, av.y * c_ - av.x * s_);
    }
    __syncthreads();

    int w = t >> 6, lane = t & 63;
    int mnR = N, mxR = -1, mnI = N, mxI = -1;
    for (int n = t; n < N; n += 256) {
        float lr = label[b * 2 * N + n];
        float li = label[b * 2 * N + N + n];
        if (fabsf(lr) > 0.01f) { mnR = min(mnR, n); mxR = max(mxR, n); }
        if (fabsf(li) > 0.01f) { mnI = min(mnI, n); mxI = max(mxI, n); }
    }
    for (int o = 32; o > 0; o >>= 1) {
        mnR = min(mnR, __shfl_down(mnR, o));
        mxR = max(mxR, __shfl_down(mxR, o));
        mnI = min(mnI, __shfl_down(mnI, o));
        mxI = max(mxI, __shfl_down(mxI, o));
    }
    if (lane == 0) { ibuf[w][0] = mnR; ibuf[w][1] = mxR; ibuf[w][2] = mnI; ibuf[w][3] = mxI; }
    __syncthreads();
    if (t == 0) {
        int a0 = N, a1 = -1, a2 = N, a3 = -1;
        for (int i = 0; i < 4; ++i) {
            a0 = min(a0, ibuf[i][0]); a1 = max(a1, ibuf[i][1]);
            a2 = min(a2, ibuf[i][2]); a3 = max(a3, ibuf[i][3]);
        }
        int fr   = (a0 == N) ? 0 : a0;
        int lstR = (a1 < 0) ? (N - 1) : a1;
        int fi   = (a2 == N) ? 0 : a2;
        int lstI = (a3 < 0) ? (N - 1) : a3;
        s_first = min(fr, fi);
        s_last  = max(lstR, lstI);
    }
    __syncthreads();
    int first = s_first, last = s_last;

    float m_r = 0.f, m_i = 0.f, m_n = 0.f, m_p = 0.f;
    for (int n = t; n < N; n += 256) {
        cf p = wk[PADC(n)];
        float lr = label[b * 2 * N + n];
        float li = label[b * 2 * N + N + n];
        bool in = (n >= first) && (n < last);
        float pm  = in ? 10.f : 1.f;
        float phm = in ? 1.f : 0.f;
        float dr = p.x - lr, di = p.y - li;
        float dn = (p.x * p.x + p.y * p.y) - (lr * lr + li * li);
        float dp = atan2f(p.y, p.x) - atan2f(li, lr);
        m_r += dr * dr * pm;
        m_i += di * di * pm;
        m_n += dn * dn * pm;
        m_p += dp * dp * phm;
    }
    for (int o = 32; o > 0; o >>= 1) {
        m_r += __shfl_down(m_r, o);
        m_i += __shfl_down(m_i, o);
        m_n += __shfl_down(m_n, o);
        m_p += __shfl_down(m_p, o);
    }
    if (lane == 0) { rbuf[w][0] = m_r; rbuf[w][1] = m_i; rbuf[w][2] = m_n; rbuf[w][3] = m_p; }
    __syncthreads();
    if (t == 0) {
        float s = 0.f;
        for (int i = 0; i < 4; ++i) s += rbuf[i][0] + rbuf[i][1] + rbuf[i][2] + rbuf[i][3];
        mseJ[b] = s * (1.f / (float)N) * 0.25f;
    }
}

// ---------------------------------------------------------------------------
// shg_k: round-7 structure + tref prefetch, spill-proofed:
//  - tvv defined UNCONDITIONALLY (waves 4-7 duplicate waves 0-3's addresses,
//    same cache lines) -> no divergent liveness
//  - __launch_bounds__(512) with no min-wave clamp -> allocator has headroom
//    (<=64 VGPR keeps 8 waves/SIMD; LDS fixes 4 blocks/CU regardless)
// ---------------------------------------------------------------------------
__global__ __launch_bounds__(NT) void shg_k(const cf* __restrict__ a,
                                            const cf* __restrict__ cag,
                                            const float* __restrict__ tref,
                                            float* __restrict__ Praw,
                                            float* __restrict__ Prt,
                                            float* __restrict__ Pmax,
                                            float* __restrict__ Pt,
                                            float* __restrict__ Ptt) {
    __shared__ cf wk[ROWS * RSTRIDE];
    int t = threadIdx.x, blk = blockIdx.x;
    int b = blk >> 8;
    int dg = (blk & 255) << 2;            // delay-indices dg..dg+3
    const cf* arow  = a   + b * N;
    const cf* carow = cag + b * N;
    int bt = t & 255, rg = t >> 8;        // butterfly id, row-pair

    // ---- prefetch: 16 tref values (unconditional; waves 4-7 mirror 0-3) ----
    float tvv[16];
    {
        int rfp = (t >> 6) & 3, g = t & 63;
        int bd_ = b * N + dg + rfp;
        const float* trow = tref + ((size_t)bd_ << 10);
        int kb = ((g & 3) << 4) | (g & 12) | (g >> 4);
#pragma unroll
        for (int u = 0; u < 4; ++u)
#pragma unroll
            for (int m = 0; m < 4; ++m)
                tvv[4*u + m] = trow[(((m + 2) & 3) << 8) | (u << 6) | kb];
    }

    // ---- stage 1 (q=256): twiddles + ca loads shared across 2 rows ----
    {
        cf w1 = twiddle((float)bt * (1.0f / 1024.0f));
        cf w2 = cmul(w1,w1), w3 = cmul(w2,w1);
        cf cav[4];
#pragma unroll
        for (int k = 0; k < 4; ++k) cav[k] = carow[(bt + 256*k + 512) & 1023];
#pragma unroll
        for (int rr = 0; rr < 2; ++rr) {
            int r = rg * 2 + rr;
            int d = dg + r;
            cf x[4];
#pragma unroll
            for (int k = 0; k < 4; ++k)
                x[k] = cmul(cav[k], arow[(bt + 256*k - d) & 1023]);
            cf y0, y1, y2, y3; bfly(x[0],x[1],x[2],x[3],y0,y1,y2,y3);
            cf* w = wk + r * RSTRIDE;
            w[P16(bt)]     = y0;
            w[P16(bt+256)] = cmul(y1,w1);
            w[P16(bt+512)] = cmul(y2,w2);
            w[P16(bt+768)] = cmul(y3,w3);
        }
    }
    __syncthreads();
    // ---- stage 2 (q=64): wave-local per row-half ----
    {
        int j = bt & 63;
        int base = ((bt >> 6) << 8) + j;
        cf w1 = twiddle((float)j * (1.0f / 256.0f));
        cf w2 = cmul(w1,w1), w3 = cmul(w2,w1);
#pragma unroll
        for (int rr = 0; rr < 2; ++rr) dif4p(wk + (rg*2+rr) * RSTRIDE, base, 64, w1, w2, w3);
    }
    WSYNC();
    // ---- stage 3 (q=16): still wave-local per row-half ----
    {
        int j = bt & 15;
        int base = ((bt >> 4) << 6) + j;
        cf w1 = twiddle((float)j * (1.0f / 64.0f));
        cf w2 = cmul(w1,w1), w3 = cmul(w2,w1);
#pragma unroll
        for (int rr = 0; rr < 2; ++rr) dif4p(wk + (rg*2+rr) * RSTRIDE, base, 16, w1, w2, w3);
    }
    __syncthreads();   // redistribution: fused stage crosses row-halves

    // ---- fused stages 4+5: in-register 16-pt DFT; wave w (w<4) = row w ----
    if (t < 256) {
        const cf W1 = { 0.923879533f, -0.382683432f};
        const cf W2 = { 0.707106781f, -0.707106781f};
        const cf W3 = { 0.382683432f, -0.923879533f};
        const cf W6 = {-0.707106781f, -0.707106781f};
        const cf W9 = {-0.923879533f,  0.382683432f};
        int r = t >> 6;                  // row = wave index
        int g = t & 63;                  // 16-block within row
        cf* w = wk + r * RSTRIDE;
        cf v[16];
        int base = 17 * g;               // P16(16g+k) = 17g+k, k<16
#pragma unroll
        for (int k = 0; k < 16; ++k) v[k] = w[base + k];
        cf o[16];
        bfly(v[0], v[4], v[8], v[12], o[0], o[4], o[8],  o[12]);
        { cf y0,y1,y2,y3; bfly(v[1],v[5],v[9], v[13],y0,y1,y2,y3);
          o[1]=y0; o[5]=cmul(y1,W1); o[9]=cmul(y2,W2); o[13]=cmul(y3,W3); }
        { cf y0,y1,y2,y3; bfly(v[2],v[6],v[10],v[14],y0,y1,y2,y3);
          o[2]=y0; o[6]=cmul(y1,W2); o[10]=make_float2(y2.y,-y2.x); o[14]=cmul(y3,W6); }
        { cf y0,y1,y2,y3; bfly(v[3],v[7],v[11],v[15],y0,y1,y2,y3);
          o[3]=y0; o[7]=cmul(y1,W3); o[11]=cmul(y2,W6); o[15]=cmul(y3,W9); }

        float sraw = 0.f, srt = 0.f, mx = 0.f, st = 0.f, stt = 0.f;
        int bd = b * N + dg + r;
#pragma unroll
        for (int u = 0; u < 4; ++u) {
            cf y0, y1, y2, y3;
            bfly(o[4*u], o[4*u+1], o[4*u+2], o[4*u+3], y0, y1, y2, y3);
            cf ys[4] = {y0, y1, y2, y3};
#pragma unroll
            for (int m = 0; m < 4; ++m) {
                float m2 = ys[m].x * ys[m].x + ys[m].y * ys[m].y;
                float tv = tvv[4*u + m];
                sraw += m2;
                srt += m2 * tv;
                mx = fmaxf(mx, m2);
                st += tv;
                stt += tv * tv;
            }
        }
        // full-wave reduction: wave r covers g = 0..63 = entire row r
        for (int o_ = 32; o_ > 0; o_ >>= 1) {
            sraw += __shfl_down(sraw, o_);
            srt  += __shfl_down(srt, o_);
            mx    = fmaxf(mx, __shfl_down(mx, o_));
            st   += __shfl_down(st, o_);
            stt  += __shfl_down(stt, o_);
        }
        if ((t & 63) == 0) {
            Praw[bd] = sraw; Prt[bd] = srt; Pmax[bd] = mx; Pt[bd] = st; Ptt[bd] = stt;
        }
    }
}

// ---------------------------------------------------------------------------
// loss_k: per batch — frog from row partials + mseJ -> atomic mean.
// ---------------------------------------------------------------------------
__global__ __launch_bounds__(256) void loss_k(const float* __restrict__ Praw,
                                              const float* __restrict__ Prt,
                                              const float* __restrict__ Pmax,
                                              const float* __restrict__ Pt,
                                              const float* __restrict__ Ptt,
                                              const float* __restrict__ mseJ,
                                              float* __restrict__ out) {
    __shared__ float rbuf[4][8];
    int tid = threadIdx.x, b = blockIdx.x;
    int w = tid >> 6, lane = tid & 63;
    float sr = 0.f, srt = 0.f, mx = 0.f, st = 0.f, stt = 0.f;
    for (int i = tid; i < N; i += 256) {
        int idx = b * N + i;
        sr += Praw[idx]; srt += Prt[idx]; mx = fmaxf(mx, Pmax[idx]);
        st += Pt[idx];   stt += Ptt[idx];
    }
    for (int o = 32; o > 0; o >>= 1) {
        sr  += __shfl_down(sr, o);
        srt += __shfl_down(srt, o);
        mx   = fmaxf(mx, __shfl_down(mx, o));
        st  += __shfl_down(st, o);
        stt += __shfl_down(stt, o);
    }
    if (lane == 0) {
        rbuf[w][0] = sr; rbuf[w][1] = srt; rbuf[w][2] = mx;
        rbuf[w][3] = st; rbuf[w][4] = stt;
    }
    __syncthreads();
    if (tid == 0) {
        float A0 = 0.f, A1 = 0.f, A2 = 0.f, A3 = 0.f, A4 = 0.f;
        for (int i = 0; i < 4; ++i) {
            A0 += rbuf[i][0]; A1 += rbuf[i][1]; A2 = fmaxf(A2, rbuf[i][2]);
            A3 += rbuf[i][3]; A4 += rbuf[i][4];
        }
        float mu = (A1 / A2) / A4;
        float diff = A0 / A2 - mu * A3;
        float frog = fabsf(diff) * (1.f / (float)N);
        atomicAdd(out, (mseJ[b] + frog) * (1.f / (float)BATCH));
    }
}

extern "C" void kernel_launch(void* const* d_in, const int* in_sizes, int n_in,
                              void* d_out, int out_size, void* d_ws, size_t ws_size,
                              hipStream_t stream) {
    (void)in_sizes; (void)n_in; (void)out_size; (void)ws_size;
    const float* pred  = (const float*)d_in[0];
    const float* label = (const float*)d_in[1];
    const float* shg   = (const float*)d_in[2];
    float* out = (float*)d_out;

    char* ws = (char*)d_ws;
    cf* a   = (cf*)ws;
    cf* ca  = a + (size_t)BATCH * N;
    float* mseJ = (float*)(ca + (size_t)BATCH * N);
    float* P = mseJ + BATCH;
    float* Praw = P;
    float* Prt  = P + (size_t)BATCH * N;
    float* Pmax = P + 2 * (size_t)BATCH * N;
    float* Pt   = P + 3 * (size_t)BATCH * N;
    float* Ptt  = P + 4 * (size_t)BATCH * N;

    hipMemsetAsync(d_out, 0, sizeof(float), stream);
    hilbert_k<<<BATCH, 256, 0, stream>>>(pred, label, a, ca, mseJ);
    shg_k<<<BATCH * 256, NT, 0, stream>>>(a, ca, shg, Praw, Prt, Pmax, Pt, Ptt);
    loss_k<<<BATCH, 256, 0, stream>>>(Praw, Prt, Pmax, Pt, Ptt, mseJ, out);
}